// Round 1
// baseline (624.359 us; speedup 1.0000x reference)
//
#include <hip/hip_runtime.h>
#include <hip/hip_bf16.h>

#define NN 50000
#define EE 800000
#define SCAN_BLOCKS 196   // 196*256 = 50176 >= NN

typedef __bf16 bf16x8_t __attribute__((ext_vector_type(8)));
typedef float f32x4_t __attribute__((ext_vector_type(4)));

__device__ __forceinline__ float silu_f(float v) {
    // v * 1/(1+exp(-v)) with v_rcp_f32 (avoids the ~9-instr precise-div sequence)
    return v * __builtin_amdgcn_rcpf(1.0f + __expf(-v));
}

// ---------------- prep: x -> bf16, weights -> transposed bf16 [n][k], dst histogram ----------------
__global__ void prep_kernel(const float* __restrict__ x,
                            const float* __restrict__ We1,
                            const float* __restrict__ We2,
                            const float* __restrict__ Wn1,
                            const float* __restrict__ Wn2,
                            const int* __restrict__ eidx,
                            __bf16* __restrict__ xb,
                            __bf16* __restrict__ We1T,
                            __bf16* __restrict__ We2T,
                            __bf16* __restrict__ Wn1T,
                            __bf16* __restrict__ Wn2T,
                            int* __restrict__ hist) {
    int tid = blockIdx.x * blockDim.x + threadIdx.x;
    int np = gridDim.x * blockDim.x;
    const int NX = NN * 128 / 4;
    for (int i = tid; i < NX; i += np) {
        float4 v = ((const float4*)x)[i];
        __bf16* o = xb + (size_t)i * 4;
        o[0] = (__bf16)v.x; o[1] = (__bf16)v.y; o[2] = (__bf16)v.z; o[3] = (__bf16)v.w;
    }
    for (int i = tid; i < 256 * 128; i += np) {
        int k = i >> 7, n = i & 127;
        We1T[n * 256 + k] = (__bf16)We1[i];
        Wn1T[n * 256 + k] = (__bf16)Wn1[i];
    }
    for (int i = tid; i < 128 * 128; i += np) {
        int k = i >> 7, n = i & 127;
        We2T[n * 128 + k] = (__bf16)We2[i];
        Wn2T[n * 128 + k] = (__bf16)Wn2[i];
    }
    for (int i = tid; i < EE; i += np) {
        atomicAdd(&hist[eidx[EE + i]], 1);
    }
}

// ---------------- counting-sort scan (3 tiny kernels) ----------------
__global__ void scan_a(const int* __restrict__ hist, int* __restrict__ bsum) {
    __shared__ int sh[256];
    int i = blockIdx.x * 256 + threadIdx.x;
    sh[threadIdx.x] = (i < NN) ? hist[i] : 0;
    __syncthreads();
    for (int s = 128; s > 0; s >>= 1) {
        if (threadIdx.x < s) sh[threadIdx.x] += sh[threadIdx.x + s];
        __syncthreads();
    }
    if (threadIdx.x == 0) bsum[blockIdx.x] = sh[0];
}

__global__ void scan_b(int* __restrict__ bsum) {
    __shared__ int sh[SCAN_BLOCKS];
    int t = threadIdx.x;
    if (t < SCAN_BLOCKS) sh[t] = bsum[t];
    __syncthreads();
    if (t == 0) {
        int acc = 0;
        for (int i = 0; i < SCAN_BLOCKS; ++i) { int v = sh[i]; sh[i] = acc; acc += v; }
    }
    __syncthreads();
    if (t < SCAN_BLOCKS) bsum[t] = sh[t];
}

__global__ void scan_c(const int* __restrict__ hist, const int* __restrict__ bsum,
                       int* __restrict__ off, int* __restrict__ cursor) {
    __shared__ int sh[256];
    int tx = threadIdx.x;
    int i = blockIdx.x * 256 + tx;
    int v = (i < NN) ? hist[i] : 0;
    sh[tx] = v;
    __syncthreads();
    for (int s = 1; s < 256; s <<= 1) {
        int add = (tx >= s) ? sh[tx - s] : 0;
        __syncthreads();
        sh[tx] += add;
        __syncthreads();
    }
    int excl = sh[tx] - v + bsum[blockIdx.x];
    if (i < NN) { off[i] = excl; cursor[i] = excl; }
    if (i == NN - 1) off[NN] = excl + v;
}

// ---------------- scatter: build sorted per-edge records (no indirection in edge kernel) ----------------
__global__ void scatter_kernel(const int* __restrict__ eidx,
                               const float* __restrict__ pos,
                               const float* __restrict__ eattr,
                               const float* __restrict__ s,
                               int* __restrict__ cursor,
                               float4* __restrict__ e_geo,
                               int2* __restrict__ e_nodes,
                               float2* __restrict__ e_gate) {
    int i = blockIdx.x * blockDim.x + threadIdx.x;
    if (i < EE) {
        int si = eidx[i];
        int di = eidx[EE + i];
        int p = atomicAdd(&cursor[di], 1);
        float dx = pos[di * 3 + 0] - pos[si * 3 + 0];
        float dy = pos[di * 3 + 1] - pos[si * 3 + 1];
        float dz = pos[di * 3 + 2] - pos[si * 3 + 2];
        e_geo[p] = make_float4(dx, dy, dz, dx * dx + dy * dy + dz * dz);
        e_nodes[p] = make_int2(si, di);
        e_gate[p] = make_float2(eattr[i], s[si]);
    }
}

// ---------------- edge kernel v5: weight fragments direct from L2 (no LDS weight staging) ----------------
// block = 256 threads (4 waves), tile = 128 sorted edges.
// D = W * X^T : A-operand = weight fragment loaded DIRECT from global (We1T/We2T are
// 96 KB total, resident in every XCD L2; a ks-slice is 8 KB so same-block waves hit L1).
// This removes the 24 per-ks barriers + 8 KB Wt array -> LDS 39.4 KB -> 4 blocks/CU.
// Result: lane(m_,q) holds edge w*16+m_ (+64 for tile 1), outcols ot*16+q*4+{0..3}.
__global__ __launch_bounds__(256, 4)
void edge_kernel(const __bf16* __restrict__ xb,
                 const float4* __restrict__ e_geo,
                 const int2* __restrict__ e_nodes,
                 const float2* __restrict__ e_gate,
                 const __bf16* __restrict__ We1T,
                 const float* __restrict__ We1,   // f32, rows 256/257 (r2, edge_attr)
                 const float* __restrict__ be1,
                 const __bf16* __restrict__ We2T,
                 const float* __restrict__ be2,
                 const float* __restrict__ Wc,
                 const float* __restrict__ bc,
                 float* __restrict__ msum,
                 float* __restrict__ coordsum) {
    __shared__ __align__(16) __bf16 A2[128 * 136];  // 34,816 B; Mf (f32 64x132) aliases
    __shared__ float s_r2[128], s_ea[128], s_sg[128], s_g[128];
    __shared__ float s_diff[128 * 3];
    __shared__ int s_dst[128], s_src[128];

    float* Mf = (float*)A2;

    const int t = threadIdx.x;
    const int e0 = blockIdx.x * 128;
    const int w = t >> 6;
    const int lane = t & 63;
    const int m_ = lane & 15;
    const int q = lane >> 4;

    // per-edge scalars: 3 coalesced loads, precomputed in sorted order
    if (t < 128) {
        float4 g = e_geo[e0 + t];
        int2 nd = e_nodes[e0 + t];
        float2 gt = e_gate[e0 + t];
        s_diff[t * 3 + 0] = g.x; s_diff[t * 3 + 1] = g.y; s_diff[t * 3 + 2] = g.z;
        s_r2[t] = g.w;
        s_ea[t] = gt.x;
        s_sg[t] = gt.y;
        s_src[t] = nd.x;
        s_dst[t] = nd.y;
    }
    __syncthreads();

    const int el0 = w * 16 + m_;
    const int el1 = 64 + w * 16 + m_;
    const int nd0 = s_dst[el0], ns0 = s_src[el0];
    const int nd1 = s_dst[el1], ns1 = s_src[el1];

    // lane-base weight fragment pointers (wf row = ot*16 + m_, cols ks*32 + q*8)
    const __bf16* wp1 = We1T + m_ * 256 + q * 8;
    const __bf16* wp2 = We2T + m_ * 128 + q * 8;

    f32x4_t acc[2][8];
#pragma unroll
    for (int et = 0; et < 2; ++et)
#pragma unroll
        for (int ot = 0; ot < 8; ++ot) acc[et][ot] = (f32x4_t){0.f, 0.f, 0.f, 0.f};

    // ---- layer 1: K = 256 (cols 0..127 = x[dst], 128..255 = x[src]), xf prefetch ----
    bf16x8_t xf0 = *(const bf16x8_t*)(xb + (long)nd0 * 128 + q * 8);
    bf16x8_t xf1 = *(const bf16x8_t*)(xb + (long)nd1 * 128 + q * 8);
#pragma unroll
    for (int ks = 0; ks < 8; ++ks) {
        bf16x8_t nxf0, nxf1;
        if (ks < 7) {
            int col = ((ks + 1) & 3) * 32 + q * 8;
            nxf0 = *(const bf16x8_t*)(xb + (long)(ks + 1 < 4 ? nd0 : ns0) * 128 + col);
            nxf1 = *(const bf16x8_t*)(xb + (long)(ks + 1 < 4 ? nd1 : ns1) * 128 + col);
        }
#pragma unroll
        for (int ot = 0; ot < 8; ++ot) {
            bf16x8_t wf = *(const bf16x8_t*)(wp1 + ot * (16 * 256) + ks * 32);
            acc[0][ot] = __builtin_amdgcn_mfma_f32_16x16x32_bf16(wf, xf0, acc[0][ot], 0, 0, 0);
            acc[1][ot] = __builtin_amdgcn_mfma_f32_16x16x32_bf16(wf, xf1, acc[1][ot], 0, 0, 0);
        }
        if (ks < 7) { xf0 = nxf0; xf1 = nxf1; }
    }

    // epilogue 1: + b + r2*W[256] + ea*W[257], SiLU -> A2 (bf16, packed writes)
#pragma unroll
    for (int et = 0; et < 2; ++et) {
        int e = et ? el1 : el0;
        float r2 = s_r2[e], ea = s_ea[e];
#pragma unroll
        for (int ot = 0; ot < 8; ++ot) {
            int oc = ot * 16 + q * 4;
            float4 b1 = *(const float4*)(be1 + oc);
            float4 w6 = *(const float4*)(We1 + 256 * 128 + oc);
            float4 w7 = *(const float4*)(We1 + 257 * 128 + oc);
            union { __bf16 h[4]; uint2 u2; } pk;
            pk.h[0] = (__bf16)silu_f(acc[et][ot][0] + b1.x + r2 * w6.x + ea * w7.x);
            pk.h[1] = (__bf16)silu_f(acc[et][ot][1] + b1.y + r2 * w6.y + ea * w7.y);
            pk.h[2] = (__bf16)silu_f(acc[et][ot][2] + b1.z + r2 * w6.z + ea * w7.z);
            pk.h[3] = (__bf16)silu_f(acc[et][ot][3] + b1.w + r2 * w6.w + ea * w7.w);
            *(uint2*)(A2 + e * 136 + oc) = pk.u2;
        }
    }
    // A2 producer/consumer is same-wave (rows el0/el1 belong to wave w), but keep one
    // cheap barrier as insurance for DS ordering across lanes.
    __syncthreads();

#pragma unroll
    for (int et = 0; et < 2; ++et)
#pragma unroll
        for (int ot = 0; ot < 8; ++ot) acc[et][ot] = (f32x4_t){0.f, 0.f, 0.f, 0.f};

    // ---- layer 2: K = 128, B-operand = A2 rows (same-wave LDS), weights direct from L2 ----
#pragma unroll
    for (int ks = 0; ks < 4; ++ks) {
        bf16x8_t af0 = *(const bf16x8_t*)(A2 + el0 * 136 + ks * 32 + q * 8);
        bf16x8_t af1 = *(const bf16x8_t*)(A2 + el1 * 136 + ks * 32 + q * 8);
#pragma unroll
        for (int ot = 0; ot < 8; ++ot) {
            bf16x8_t wf = *(const bf16x8_t*)(wp2 + ot * (16 * 128) + ks * 32);
            acc[0][ot] = __builtin_amdgcn_mfma_f32_16x16x32_bf16(wf, af0, acc[0][ot], 0, 0, 0);
            acc[1][ot] = __builtin_amdgcn_mfma_f32_16x16x32_bf16(wf, af1, acc[1][ot], 0, 0, 0);
        }
    }

    // epilogue 2: + b, SiLU, * s[src]; gamma via q-lane shuffle reduce
    {
        float sg0 = s_sg[el0], sg1 = s_sg[el1];
        float gp0 = 0.f, gp1 = 0.f;
#pragma unroll
        for (int ot = 0; ot < 8; ++ot) {
            int oc = ot * 16 + q * 4;
            float4 b2 = *(const float4*)(be2 + oc);
            float4 wc = *(const float4*)(Wc + oc);
            f32x4_t v0 = acc[0][ot], v1 = acc[1][ot];
            v0[0] = silu_f(v0[0] + b2.x) * sg0; v0[1] = silu_f(v0[1] + b2.y) * sg0;
            v0[2] = silu_f(v0[2] + b2.z) * sg0; v0[3] = silu_f(v0[3] + b2.w) * sg0;
            v1[0] = silu_f(v1[0] + b2.x) * sg1; v1[1] = silu_f(v1[1] + b2.y) * sg1;
            v1[2] = silu_f(v1[2] + b2.z) * sg1; v1[3] = silu_f(v1[3] + b2.w) * sg1;
            acc[0][ot] = v0; acc[1][ot] = v1;
            gp0 += v0[0] * wc.x + v0[1] * wc.y + v0[2] * wc.z + v0[3] * wc.w;
            gp1 += v1[0] * wc.x + v1[1] * wc.y + v1[2] * wc.z + v1[3] * wc.w;
        }
        gp0 += __shfl_xor(gp0, 16); gp0 += __shfl_xor(gp0, 32);
        gp1 += __shfl_xor(gp1, 16); gp1 += __shfl_xor(gp1, 32);
        if (q == 0) {
            float b0 = bc[0];
            s_g[el0] = gp0 + b0;
            s_g[el1] = gp1 + b0;
        }
    }
    __syncthreads();   // P0: all A2 reads done (Mf aliases), s_g visible

    // coord: 24 threads, 3 axes x 8 row-chunks of 16 (atomics make chunk splits safe)
    if (t < 24) {
        int ax = t % 3, ch = t / 3;
        int base = ch * 16;
        float run = 0.f;
        int cur = s_dst[base];
        for (int r = 0; r < 16; ++r) {
            int rr = base + r;
            int d = s_dst[rr];
            if (d != cur) {
                atomicAdd(&coordsum[cur * 3 + ax], run);
                run = 0.f; cur = d;
            }
            run += s_g[rr] * s_diff[rr * 3 + ax];
        }
        atomicAdd(&coordsum[cur * 3 + ax], run);
    }

    // msum: two phases of 64 edges; all 256 threads (col x row-half), serial length 32
#pragma unroll
    for (int ph = 0; ph < 2; ++ph) {
        int lr = w * 16 + m_;
#pragma unroll
        for (int ot = 0; ot < 8; ++ot)
            *(f32x4_t*)(Mf + lr * 132 + ot * 16 + q * 4) = acc[ph][ot];
        __syncthreads();   // Mf complete
        {
            int c = t & 127;
            int half = t >> 7;               // wave-uniform (waves 0,1 -> 0; 2,3 -> 1)
            int base = ph * 64 + half * 32;
            float run = 0.f;
            int cur = s_dst[base];
            for (int r = 0; r < 32; ++r) {
                int d = s_dst[base + r];     // wave-uniform branch
                if (d != cur) {
                    atomicAdd(&msum[(long)cur * 128 + c], run);
                    run = 0.f; cur = d;
                }
                run += Mf[(half * 32 + r) * 132 + c];
            }
            atomicAdd(&msum[(long)cur * 128 + c], run);
        }
        __syncthreads();   // reduce done before Mf overwrite / exit
    }
}

// ---------------- node kernel: normalize agg + 2-layer node MLP + pos update ----------------
__global__ __launch_bounds__(256, 2)
void node_kernel(const __bf16* __restrict__ xb,
                 const float* __restrict__ msum,
                 const int* __restrict__ off,
                 const __bf16* __restrict__ Wn1T,
                 const float* __restrict__ bn1,
                 const __bf16* __restrict__ Wn2T,
                 const float* __restrict__ bn2,
                 const float* __restrict__ pos,
                 const float* __restrict__ csum,
                 float* __restrict__ xout,
                 float* __restrict__ pout) {
    __shared__ __align__(16) __bf16 Abf[64 * 264];
    __shared__ __align__(16) __bf16 Wt[128 * 56];
    __shared__ __align__(16) __bf16 A2[64 * 136];

    const int t = threadIdx.x;
    const int r0 = blockIdx.x * 64;
    const int w = t >> 6;
    const int lane = t & 63;
    const int m_ = lane & 15;
    const int q = lane >> 4;

    // pos update for this block's 64 nodes (independent of the MLP)
    if (t < 192) {
        int node = r0 + t / 3;
        if (node < NN) {
            int dg = off[node + 1] - off[node];
            float inv = 1.f / (float)(dg < 1 ? 1 : dg);
            int fl = node * 3 + t % 3;
            pout[fl] = pos[fl] + csum[fl] * inv;
        }
    }

    for (int i = 0; i < 8; ++i) {
        int id = t + 256 * i;
        int rl = id >> 5, ch = id & 31;
        int row = r0 + rl;
        int c8 = (ch & 15) * 8;
        union { __bf16 h[8]; uint4 u; } pk;
        if (row < NN) {
            if (ch < 16) {
                pk.u = *(const uint4*)(xb + (long)row * 128 + c8);
            } else {
                const float* mp = msum + (long)row * 128 + c8;
                int dg = off[row + 1] - off[row];
                float inv = 1.f / (float)(dg < 1 ? 1 : dg);
#pragma unroll
                for (int j = 0; j < 8; ++j) pk.h[j] = (__bf16)(mp[j] * inv);
            }
        } else {
            pk.u = make_uint4(0, 0, 0, 0);
        }
        *(uint4*)(Abf + rl * 264 + ((ch < 16) ? 0 : 128) + c8) = pk.u;
    }
    __syncthreads();

    f32x4_t acc[8];
#pragma unroll
    for (int ct = 0; ct < 8; ++ct) acc[ct] = (f32x4_t){0.f, 0.f, 0.f, 0.f};

    for (int ks = 0; ks < 8; ++ks) {
#pragma unroll
        for (int i = 0; i < 2; ++i) {
            int c = t + 256 * i;
            int n = c >> 2, ko = (c & 3) * 8;
            uint4 v = *(const uint4*)(Wn1T + n * 256 + ks * 32 + ko);
            *(uint4*)(Wt + n * 56 + ko) = v;
        }
        __syncthreads();
        bf16x8_t a = *(const bf16x8_t*)(Abf + (w * 16 + m_) * 264 + ks * 32 + q * 8);
#pragma unroll
        for (int ct = 0; ct < 8; ++ct) {
            bf16x8_t b = *(const bf16x8_t*)(Wt + (ct * 16 + m_) * 56 + q * 8);
            acc[ct] = __builtin_amdgcn_mfma_f32_16x16x32_bf16(a, b, acc[ct], 0, 0, 0);
        }
        __syncthreads();
    }
#pragma unroll
    for (int ct = 0; ct < 8; ++ct) {
        int c = ct * 16 + m_;
        float b1 = bn1[c];
#pragma unroll
        for (int r = 0; r < 4; ++r) {
            int el = w * 16 + q * 4 + r;
            float v = acc[ct][r] + b1;
            A2[el * 136 + c] = (__bf16)silu_f(v);
        }
    }
    __syncthreads();

#pragma unroll
    for (int ct = 0; ct < 8; ++ct) acc[ct] = (f32x4_t){0.f, 0.f, 0.f, 0.f};

    for (int ks = 0; ks < 4; ++ks) {
#pragma unroll
        for (int i = 0; i < 2; ++i) {
            int c = t + 256 * i;
            int n = c >> 2, ko = (c & 3) * 8;
            uint4 v = *(const uint4*)(Wn2T + n * 128 + ks * 32 + ko);
            *(uint4*)(Wt + n * 56 + ko) = v;
        }
        __syncthreads();
        bf16x8_t a = *(const bf16x8_t*)(A2 + (w * 16 + m_) * 136 + ks * 32 + q * 8);
#pragma unroll
        for (int ct = 0; ct < 8; ++ct) {
            bf16x8_t b = *(const bf16x8_t*)(Wt + (ct * 16 + m_) * 56 + q * 8);
            acc[ct] = __builtin_amdgcn_mfma_f32_16x16x32_bf16(a, b, acc[ct], 0, 0, 0);
        }
        __syncthreads();
    }
#pragma unroll
    for (int ct = 0; ct < 8; ++ct) {
        int c = ct * 16 + m_;
        float b2 = bn2[c];
#pragma unroll
        for (int r = 0; r < 4; ++r) {
            int el = w * 16 + q * 4 + r;
            int row = r0 + el;
            if (row < NN) xout[(long)row * 128 + c] = acc[ct][r] + b2;
        }
    }
}

extern "C" void kernel_launch(void* const* d_in, const int* in_sizes, int n_in,
                              void* d_out, int out_size, void* d_ws, size_t ws_size,
                              hipStream_t stream) {
    const float* x     = (const float*)d_in[0];
    const float* pos   = (const float*)d_in[1];
    const int*   eidx  = (const int*)d_in[2];
    const float* eattr = (const float*)d_in[3];
    const float* s     = (const float*)d_in[4];
    const float* We1   = (const float*)d_in[5];
    const float* be1   = (const float*)d_in[6];
    const float* We2   = (const float*)d_in[7];
    const float* be2   = (const float*)d_in[8];
    const float* Wn1   = (const float*)d_in[9];
    const float* bn1   = (const float*)d_in[10];
    const float* Wn2   = (const float*)d_in[11];
    const float* bn2   = (const float*)d_in[12];
    const float* Wc    = (const float*)d_in[13];
    const float* bc    = (const float*)d_in[14];

    char* ws = (char*)d_ws;
    __bf16* xb     = (__bf16*)(ws);                 // 12,800,000
    __bf16* We1T   = (__bf16*)(ws + 12800000);      //     65,536
    __bf16* We2T   = (__bf16*)(ws + 12865536);      //     32,768
    __bf16* Wn1T   = (__bf16*)(ws + 12898304);      //     65,536
    __bf16* Wn2T   = (__bf16*)(ws + 12963840);      //     32,768
    float*  msum   = (float*)(ws + 12996608);       // 25,600,000
    float*  csum   = (float*)(ws + 38596608);       //    600,000
    int*    hist   = (int*)(ws + 39196608);         //    200,000
    int*    off    = (int*)(ws + 39396608);         //    200,064
    int*    cursor = (int*)(ws + 39596672);         //    200,064
    float4* e_geo  = (float4*)(ws + 39796736);      // 12,800,000 (16B aligned)
    int2*   e_nodes= (int2*)(ws + 52596736);        //  6,400,000
    float2* e_gate = (float2*)(ws + 58996736);      //  6,400,000
    int*    bsum   = (int*)(ws + 65396736);         //      1,024 (end 65,397,760)

    float* xout = (float*)d_out;
    float* pout = xout + (size_t)NN * 128;

    // zero msum + csum + hist (contiguous, 26.4 MB)
    hipMemsetAsync(ws + 12996608, 0, 26400000, stream);
    prep_kernel<<<1024, 256, 0, stream>>>(x, We1, We2, Wn1, Wn2, eidx,
                                          xb, We1T, We2T, Wn1T, Wn2T, hist);
    scan_a<<<SCAN_BLOCKS, 256, 0, stream>>>(hist, bsum);
    scan_b<<<1, 256, 0, stream>>>(bsum);
    scan_c<<<SCAN_BLOCKS, 256, 0, stream>>>(hist, bsum, off, cursor);
    scatter_kernel<<<(EE + 255) / 256, 256, 0, stream>>>(eidx, pos, eattr, s, cursor,
                                                         e_geo, e_nodes, e_gate);
    edge_kernel<<<EE / 128, 256, 0, stream>>>(xb, e_geo, e_nodes, e_gate,
                                              We1T, We1, be1, We2T, be2, Wc, bc,
                                              msum, csum);
    node_kernel<<<(NN + 63) / 64, 256, 0, stream>>>(xb, msum, off, Wn1T, bn1, Wn2T, bn2,
                                                    pos, csum, xout, pout);
}

// Round 2
// 406.050 us; speedup vs baseline: 1.5376x; 1.5376x over previous
//
#include <hip/hip_runtime.h>
#include <hip/hip_bf16.h>

#define NN 50000
#define EE 800000
#define SCAN_BLOCKS 196   // 196*256 = 50176 >= NN

typedef __bf16 bf16x8_t __attribute__((ext_vector_type(8)));
typedef float f32x4_t __attribute__((ext_vector_type(4)));

__device__ __forceinline__ float silu_f(float v) {
    // v * 1/(1+exp(-v)) with v_rcp_f32 (avoids the ~9-instr precise-div sequence)
    return v * __builtin_amdgcn_rcpf(1.0f + __expf(-v));
}

// ---------------- prep: x -> bf16, weights -> k-slice-major bf16, dst histogram ----------------
// We1S layout: [ks(8)][row(128)][chunk(32)] bf16  (row = out-neuron, chunk = k within slice)
// We2S layout: [ks(4)][row(128)][chunk(32)] bf16
// Wn1T/Wn2T stay [n][k] for the node kernel.
__global__ void prep_kernel(const float* __restrict__ x,
                            const float* __restrict__ We1,
                            const float* __restrict__ We2,
                            const float* __restrict__ Wn1,
                            const float* __restrict__ Wn2,
                            const int* __restrict__ eidx,
                            __bf16* __restrict__ xb,
                            __bf16* __restrict__ We1S,
                            __bf16* __restrict__ We2S,
                            __bf16* __restrict__ Wn1T,
                            __bf16* __restrict__ Wn2T,
                            int* __restrict__ hist) {
    int tid = blockIdx.x * blockDim.x + threadIdx.x;
    int np = gridDim.x * blockDim.x;
    const int NX = NN * 128 / 4;
    for (int i = tid; i < NX; i += np) {
        float4 v = ((const float4*)x)[i];
        __bf16* o = xb + (size_t)i * 4;
        o[0] = (__bf16)v.x; o[1] = (__bf16)v.y; o[2] = (__bf16)v.z; o[3] = (__bf16)v.w;
    }
    for (int i = tid; i < 256 * 128; i += np) {
        int k = i >> 7, n = i & 127;
        We1S[(k >> 5) * 4096 + n * 32 + (k & 31)] = (__bf16)We1[i];
        Wn1T[n * 256 + k] = (__bf16)Wn1[i];
    }
    for (int i = tid; i < 128 * 128; i += np) {
        int k = i >> 7, n = i & 127;
        We2S[(k >> 5) * 4096 + n * 32 + (k & 31)] = (__bf16)We2[i];
        Wn2T[n * 128 + k] = (__bf16)Wn2[i];
    }
    for (int i = tid; i < EE; i += np) {
        atomicAdd(&hist[eidx[EE + i]], 1);
    }
}

// ---------------- counting-sort scan (3 tiny kernels) ----------------
__global__ void scan_a(const int* __restrict__ hist, int* __restrict__ bsum) {
    __shared__ int sh[256];
    int i = blockIdx.x * 256 + threadIdx.x;
    sh[threadIdx.x] = (i < NN) ? hist[i] : 0;
    __syncthreads();
    for (int s = 128; s > 0; s >>= 1) {
        if (threadIdx.x < s) sh[threadIdx.x] += sh[threadIdx.x + s];
        __syncthreads();
    }
    if (threadIdx.x == 0) bsum[blockIdx.x] = sh[0];
}

__global__ void scan_b(int* __restrict__ bsum) {
    __shared__ int sh[SCAN_BLOCKS];
    int t = threadIdx.x;
    if (t < SCAN_BLOCKS) sh[t] = bsum[t];
    __syncthreads();
    if (t == 0) {
        int acc = 0;
        for (int i = 0; i < SCAN_BLOCKS; ++i) { int v = sh[i]; sh[i] = acc; acc += v; }
    }
    __syncthreads();
    if (t < SCAN_BLOCKS) bsum[t] = sh[t];
}

__global__ void scan_c(const int* __restrict__ hist, const int* __restrict__ bsum,
                       int* __restrict__ off, int* __restrict__ cursor) {
    __shared__ int sh[256];
    int tx = threadIdx.x;
    int i = blockIdx.x * 256 + tx;
    int v = (i < NN) ? hist[i] : 0;
    sh[tx] = v;
    __syncthreads();
    for (int s = 1; s < 256; s <<= 1) {
        int add = (tx >= s) ? sh[tx - s] : 0;
        __syncthreads();
        sh[tx] += add;
        __syncthreads();
    }
    int excl = sh[tx] - v + bsum[blockIdx.x];
    if (i < NN) { off[i] = excl; cursor[i] = excl; }
    if (i == NN - 1) off[NN] = excl + v;
}

// ---------------- scatter: build sorted per-edge records (no indirection in edge kernel) ----------------
__global__ void scatter_kernel(const int* __restrict__ eidx,
                               const float* __restrict__ pos,
                               const float* __restrict__ eattr,
                               const float* __restrict__ s,
                               int* __restrict__ cursor,
                               float4* __restrict__ e_geo,
                               int2* __restrict__ e_nodes,
                               float2* __restrict__ e_gate) {
    int i = blockIdx.x * blockDim.x + threadIdx.x;
    if (i < EE) {
        int si = eidx[i];
        int di = eidx[EE + i];
        int p = atomicAdd(&cursor[di], 1);
        float dx = pos[di * 3 + 0] - pos[si * 3 + 0];
        float dy = pos[di * 3 + 1] - pos[si * 3 + 1];
        float dz = pos[di * 3 + 2] - pos[si * 3 + 2];
        e_geo[p] = make_float4(dx, dy, dz, dx * dx + dy * dy + dz * dz);
        e_nodes[p] = make_int2(si, di);
        e_gate[p] = make_float2(eattr[i], s[si]);
    }
}

// ---------------- edge kernel v6: r0 structure + Wt XOR swizzle + coalesced staging ----------------
// block = 256 threads (4 waves), tile = 128 sorted edges.
// D = W * X^T : A-operand = weight k-slice in LDS (XOR-swizzled chunks, 2-way max),
// B-operand = 16B direct global x loads.
// Wt chunk swizzle: physical_chunk = chunk ^ ((row>>1)&3). Write side: row=t>>2 (+64),
// chunk=t&3 -> same ((t>>2)>>1)&3. Read side: row=ot*16+m_, chunk=q -> (m_>>1)&3.
// Result: lane(m_,q) holds edge w*16+m_ (+64 for tile 1), outcols ot*16+q*4+{0..3}.
__global__ __launch_bounds__(256, 3)
void edge_kernel(const __bf16* __restrict__ xb,
                 const float4* __restrict__ e_geo,
                 const int2* __restrict__ e_nodes,
                 const float2* __restrict__ e_gate,
                 const __bf16* __restrict__ We1S,
                 const float* __restrict__ We1,   // f32, rows 256/257 (r2, edge_attr)
                 const float* __restrict__ be1,
                 const __bf16* __restrict__ We2S,
                 const float* __restrict__ be2,
                 const float* __restrict__ Wc,
                 const float* __restrict__ bc,
                 float* __restrict__ msum,
                 float* __restrict__ coordsum) {
    __shared__ __align__(16) __bf16 Wt[128 * 32];   //  8,192 B
    __shared__ __align__(16) __bf16 A2[128 * 136];  // 34,816 B; Mf (f32 64x132) aliases
    __shared__ float s_r2[128], s_ea[128], s_sg[128], s_g[128];
    __shared__ float s_diff[128 * 3];
    __shared__ int s_dst[128], s_src[128];

    float* Mf = (float*)A2;

    const int t = threadIdx.x;
    const int e0 = blockIdx.x * 128;
    const int w = t >> 6;
    const int lane = t & 63;
    const int m_ = lane & 15;
    const int q = lane >> 4;

    // per-edge scalars: 3 coalesced loads, precomputed in sorted order
    if (t < 128) {
        float4 g = e_geo[e0 + t];
        int2 nd = e_nodes[e0 + t];
        float2 gt = e_gate[e0 + t];
        s_diff[t * 3 + 0] = g.x; s_diff[t * 3 + 1] = g.y; s_diff[t * 3 + 2] = g.z;
        s_r2[t] = g.w;
        s_ea[t] = gt.x;
        s_sg[t] = gt.y;
        s_src[t] = nd.x;
        s_dst[t] = nd.y;
    }
    __syncthreads();

    const int el0 = w * 16 + m_;
    const int el1 = 64 + w * 16 + m_;
    const int nd0 = s_dst[el0], ns0 = s_src[el0];
    const int nd1 = s_dst[el1], ns1 = s_src[el1];

    f32x4_t acc[2][8];
#pragma unroll
    for (int et = 0; et < 2; ++et)
#pragma unroll
        for (int ot = 0; ot < 8; ++ot) acc[et][ot] = (f32x4_t){0.f, 0.f, 0.f, 0.f};

    // staging addresses: coalesced (8 KB slice = 256 threads x 2 x 16 B contiguous)
    // thread t covers slice elements [t*8, t*8+8) and [2048 + t*8, ...)
    const int wrow = t >> 2;                    // logical row of first write (0..63)
    const int pch = (t & 3) ^ ((wrow >> 1) & 3);  // swizzled physical chunk
    const int wofs = wrow * 32 + pch * 8;       // bf16 offset of first write
    // wf read offset base (row = ot*16+m_, physical chunk = q ^ ((m_>>1)&3))
    const int rofs = m_ * 32 + (q ^ ((m_ >> 1) & 3)) * 8;

    // ---- layer 1: K = 256 (cols 0..127 = x[dst], 128..255 = x[src]), xf + Wt prefetch ----
    bf16x8_t xf0 = *(const bf16x8_t*)(xb + (long)nd0 * 128 + q * 8);
    bf16x8_t xf1 = *(const bf16x8_t*)(xb + (long)nd1 * 128 + q * 8);
    uint4 v0 = *(const uint4*)(We1S + t * 8);
    uint4 v1 = *(const uint4*)(We1S + 2048 + t * 8);
#pragma unroll
    for (int ks = 0; ks < 8; ++ks) {
        __syncthreads();                         // prior wf reads done
        *(uint4*)(Wt + wofs) = v0;
        *(uint4*)(Wt + 64 * 32 + wofs) = v1;
        bf16x8_t nxf0, nxf1;
        uint4 nv0, nv1;
        if (ks < 7) {
            int col = ((ks + 1) & 3) * 32 + q * 8;
            nxf0 = *(const bf16x8_t*)(xb + (long)(ks + 1 < 4 ? nd0 : ns0) * 128 + col);
            nxf1 = *(const bf16x8_t*)(xb + (long)(ks + 1 < 4 ? nd1 : ns1) * 128 + col);
            nv0 = *(const uint4*)(We1S + (ks + 1) * 4096 + t * 8);
            nv1 = *(const uint4*)(We1S + (ks + 1) * 4096 + 2048 + t * 8);
        }
        __syncthreads();                         // Wt ready
#pragma unroll
        for (int ot = 0; ot < 8; ++ot) {
            bf16x8_t wf = *(const bf16x8_t*)(Wt + ot * (16 * 32) + rofs);
            acc[0][ot] = __builtin_amdgcn_mfma_f32_16x16x32_bf16(wf, xf0, acc[0][ot], 0, 0, 0);
            acc[1][ot] = __builtin_amdgcn_mfma_f32_16x16x32_bf16(wf, xf1, acc[1][ot], 0, 0, 0);
        }
        if (ks < 7) { xf0 = nxf0; xf1 = nxf1; v0 = nv0; v1 = nv1; }
    }

    // epilogue 1: + b + r2*W[256] + ea*W[257], SiLU -> A2 (bf16, packed writes)
#pragma unroll
    for (int et = 0; et < 2; ++et) {
        int e = et ? el1 : el0;
        float r2 = s_r2[e], ea = s_ea[e];
#pragma unroll
        for (int ot = 0; ot < 8; ++ot) {
            int oc = ot * 16 + q * 4;
            float4 b1 = *(const float4*)(be1 + oc);
            float4 w6 = *(const float4*)(We1 + 256 * 128 + oc);
            float4 w7 = *(const float4*)(We1 + 257 * 128 + oc);
            union { __bf16 h[4]; uint2 u2; } pk;
            pk.h[0] = (__bf16)silu_f(acc[et][ot][0] + b1.x + r2 * w6.x + ea * w7.x);
            pk.h[1] = (__bf16)silu_f(acc[et][ot][1] + b1.y + r2 * w6.y + ea * w7.y);
            pk.h[2] = (__bf16)silu_f(acc[et][ot][2] + b1.z + r2 * w6.z + ea * w7.z);
            pk.h[3] = (__bf16)silu_f(acc[et][ot][3] + b1.w + r2 * w6.w + ea * w7.w);
            *(uint2*)(A2 + e * 136 + oc) = pk.u2;
        }
    }

#pragma unroll
    for (int et = 0; et < 2; ++et)
#pragma unroll
        for (int ot = 0; ot < 8; ++ot) acc[et][ot] = (f32x4_t){0.f, 0.f, 0.f, 0.f};

    // ---- layer 2: K = 128, B-operand = A2 rows (same-wave LDS) ----
    uint4 w20 = *(const uint4*)(We2S + t * 8);
    uint4 w21 = *(const uint4*)(We2S + 2048 + t * 8);
    for (int ks = 0; ks < 4; ++ks) {
        __syncthreads();                         // prior wf reads + (ks=0) A2 writes done
        *(uint4*)(Wt + wofs) = w20;
        *(uint4*)(Wt + 64 * 32 + wofs) = w21;
        if (ks < 3) {
            w20 = *(const uint4*)(We2S + (ks + 1) * 4096 + t * 8);
            w21 = *(const uint4*)(We2S + (ks + 1) * 4096 + 2048 + t * 8);
        }
        __syncthreads();                         // Wt ready
        bf16x8_t af0 = *(const bf16x8_t*)(A2 + el0 * 136 + ks * 32 + q * 8);
        bf16x8_t af1 = *(const bf16x8_t*)(A2 + el1 * 136 + ks * 32 + q * 8);
#pragma unroll
        for (int ot = 0; ot < 8; ++ot) {
            bf16x8_t wf = *(const bf16x8_t*)(Wt + ot * (16 * 32) + rofs);
            acc[0][ot] = __builtin_amdgcn_mfma_f32_16x16x32_bf16(wf, af0, acc[0][ot], 0, 0, 0);
            acc[1][ot] = __builtin_amdgcn_mfma_f32_16x16x32_bf16(wf, af1, acc[1][ot], 0, 0, 0);
        }
    }

    // epilogue 2: + b, SiLU, * s[src]; gamma via q-lane shuffle reduce
    {
        float sg0 = s_sg[el0], sg1 = s_sg[el1];
        float gp0 = 0.f, gp1 = 0.f;
#pragma unroll
        for (int ot = 0; ot < 8; ++ot) {
            int oc = ot * 16 + q * 4;
            float4 b2 = *(const float4*)(be2 + oc);
            float4 wc = *(const float4*)(Wc + oc);
            f32x4_t v0_ = acc[0][ot], v1_ = acc[1][ot];
            v0_[0] = silu_f(v0_[0] + b2.x) * sg0; v0_[1] = silu_f(v0_[1] + b2.y) * sg0;
            v0_[2] = silu_f(v0_[2] + b2.z) * sg0; v0_[3] = silu_f(v0_[3] + b2.w) * sg0;
            v1_[0] = silu_f(v1_[0] + b2.x) * sg1; v1_[1] = silu_f(v1_[1] + b2.y) * sg1;
            v1_[2] = silu_f(v1_[2] + b2.z) * sg1; v1_[3] = silu_f(v1_[3] + b2.w) * sg1;
            acc[0][ot] = v0_; acc[1][ot] = v1_;
            gp0 += v0_[0] * wc.x + v0_[1] * wc.y + v0_[2] * wc.z + v0_[3] * wc.w;
            gp1 += v1_[0] * wc.x + v1_[1] * wc.y + v1_[2] * wc.z + v1_[3] * wc.w;
        }
        gp0 += __shfl_xor(gp0, 16); gp0 += __shfl_xor(gp0, 32);
        gp1 += __shfl_xor(gp1, 16); gp1 += __shfl_xor(gp1, 32);
        if (q == 0) {
            float b0 = bc[0];
            s_g[el0] = gp0 + b0;
            s_g[el1] = gp1 + b0;
        }
    }
    __syncthreads();   // P0: all A2 reads done (Mf aliases), s_g visible

    // coord: 24 threads, 3 axes x 8 row-chunks of 16 (atomics make chunk splits safe)
    if (t < 24) {
        int ax = t % 3, ch = t / 3;
        int base = ch * 16;
        float run = 0.f;
        int cur = s_dst[base];
        for (int r = 0; r < 16; ++r) {
            int rr = base + r;
            int d = s_dst[rr];
            if (d != cur) {
                atomicAdd(&coordsum[cur * 3 + ax], run);
                run = 0.f; cur = d;
            }
            run += s_g[rr] * s_diff[rr * 3 + ax];
        }
        atomicAdd(&coordsum[cur * 3 + ax], run);
    }

    // msum: two phases of 64 edges; all 256 threads (col x row-half), serial length 32
#pragma unroll
    for (int ph = 0; ph < 2; ++ph) {
        int lr = w * 16 + m_;
#pragma unroll
        for (int ot = 0; ot < 8; ++ot)
            *(f32x4_t*)(Mf + lr * 132 + ot * 16 + q * 4) = acc[ph][ot];
        __syncthreads();   // Mf complete
        {
            int c = t & 127;
            int half = t >> 7;               // wave-uniform (waves 0,1 -> 0; 2,3 -> 1)
            int base = ph * 64 + half * 32;
            float run = 0.f;
            int cur = s_dst[base];
            for (int r = 0; r < 32; ++r) {
                int d = s_dst[base + r];     // wave-uniform branch
                if (d != cur) {
                    atomicAdd(&msum[(long)cur * 128 + c], run);
                    run = 0.f; cur = d;
                }
                run += Mf[(half * 32 + r) * 132 + c];
            }
            atomicAdd(&msum[(long)cur * 128 + c], run);
        }
        __syncthreads();   // reduce done before Mf overwrite / exit
    }
}

// ---------------- node kernel: normalize agg + 2-layer node MLP + pos update ----------------
__global__ __launch_bounds__(256, 2)
void node_kernel(const __bf16* __restrict__ xb,
                 const float* __restrict__ msum,
                 const int* __restrict__ off,
                 const __bf16* __restrict__ Wn1T,
                 const float* __restrict__ bn1,
                 const __bf16* __restrict__ Wn2T,
                 const float* __restrict__ bn2,
                 const float* __restrict__ pos,
                 const float* __restrict__ csum,
                 float* __restrict__ xout,
                 float* __restrict__ pout) {
    __shared__ __align__(16) __bf16 Abf[64 * 264];
    __shared__ __align__(16) __bf16 Wt[128 * 56];
    __shared__ __align__(16) __bf16 A2[64 * 136];

    const int t = threadIdx.x;
    const int r0 = blockIdx.x * 64;
    const int w = t >> 6;
    const int lane = t & 63;
    const int m_ = lane & 15;
    const int q = lane >> 4;

    // pos update for this block's 64 nodes (independent of the MLP)
    if (t < 192) {
        int node = r0 + t / 3;
        if (node < NN) {
            int dg = off[node + 1] - off[node];
            float inv = 1.f / (float)(dg < 1 ? 1 : dg);
            int fl = node * 3 + t % 3;
            pout[fl] = pos[fl] + csum[fl] * inv;
        }
    }

    for (int i = 0; i < 8; ++i) {
        int id = t + 256 * i;
        int rl = id >> 5, ch = id & 31;
        int row = r0 + rl;
        int c8 = (ch & 15) * 8;
        union { __bf16 h[8]; uint4 u; } pk;
        if (row < NN) {
            if (ch < 16) {
                pk.u = *(const uint4*)(xb + (long)row * 128 + c8);
            } else {
                const float* mp = msum + (long)row * 128 + c8;
                int dg = off[row + 1] - off[row];
                float inv = 1.f / (float)(dg < 1 ? 1 : dg);
#pragma unroll
                for (int j = 0; j < 8; ++j) pk.h[j] = (__bf16)(mp[j] * inv);
            }
        } else {
            pk.u = make_uint4(0, 0, 0, 0);
        }
        *(uint4*)(Abf + rl * 264 + ((ch < 16) ? 0 : 128) + c8) = pk.u;
    }
    __syncthreads();

    f32x4_t acc[8];
#pragma unroll
    for (int ct = 0; ct < 8; ++ct) acc[ct] = (f32x4_t){0.f, 0.f, 0.f, 0.f};

    for (int ks = 0; ks < 8; ++ks) {
#pragma unroll
        for (int i = 0; i < 2; ++i) {
            int c = t + 256 * i;
            int n = c >> 2, ko = (c & 3) * 8;
            uint4 v = *(const uint4*)(Wn1T + n * 256 + ks * 32 + ko);
            *(uint4*)(Wt + n * 56 + ko) = v;
        }
        __syncthreads();
        bf16x8_t a = *(const bf16x8_t*)(Abf + (w * 16 + m_) * 264 + ks * 32 + q * 8);
#pragma unroll
        for (int ct = 0; ct < 8; ++ct) {
            bf16x8_t b = *(const bf16x8_t*)(Wt + (ct * 16 + m_) * 56 + q * 8);
            acc[ct] = __builtin_amdgcn_mfma_f32_16x16x32_bf16(a, b, acc[ct], 0, 0, 0);
        }
        __syncthreads();
    }
#pragma unroll
    for (int ct = 0; ct < 8; ++ct) {
        int c = ct * 16 + m_;
        float b1 = bn1[c];
#pragma unroll
        for (int r = 0; r < 4; ++r) {
            int el = w * 16 + q * 4 + r;
            float v = acc[ct][r] + b1;
            A2[el * 136 + c] = (__bf16)silu_f(v);
        }
    }
    __syncthreads();

#pragma unroll
    for (int ct = 0; ct < 8; ++ct) acc[ct] = (f32x4_t){0.f, 0.f, 0.f, 0.f};

    for (int ks = 0; ks < 4; ++ks) {
#pragma unroll
        for (int i = 0; i < 2; ++i) {
            int c = t + 256 * i;
            int n = c >> 2, ko = (c & 3) * 8;
            uint4 v = *(const uint4*)(Wn2T + n * 128 + ks * 32 + ko);
            *(uint4*)(Wt + n * 56 + ko) = v;
        }
        __syncthreads();
        bf16x8_t a = *(const bf16x8_t*)(A2 + (w * 16 + m_) * 136 + ks * 32 + q * 8);
#pragma unroll
        for (int ct = 0; ct < 8; ++ct) {
            bf16x8_t b = *(const bf16x8_t*)(Wt + (ct * 16 + m_) * 56 + q * 8);
            acc[ct] = __builtin_amdgcn_mfma_f32_16x16x32_bf16(a, b, acc[ct], 0, 0, 0);
        }
        __syncthreads();
    }
#pragma unroll
    for (int ct = 0; ct < 8; ++ct) {
        int c = ct * 16 + m_;
        float b2 = bn2[c];
#pragma unroll
        for (int r = 0; r < 4; ++r) {
            int el = w * 16 + q * 4 + r;
            int row = r0 + el;
            if (row < NN) xout[(long)row * 128 + c] = acc[ct][r] + b2;
        }
    }
}

extern "C" void kernel_launch(void* const* d_in, const int* in_sizes, int n_in,
                              void* d_out, int out_size, void* d_ws, size_t ws_size,
                              hipStream_t stream) {
    const float* x     = (const float*)d_in[0];
    const float* pos   = (const float*)d_in[1];
    const int*   eidx  = (const int*)d_in[2];
    const float* eattr = (const float*)d_in[3];
    const float* s     = (const float*)d_in[4];
    const float* We1   = (const float*)d_in[5];
    const float* be1   = (const float*)d_in[6];
    const float* We2   = (const float*)d_in[7];
    const float* be2   = (const float*)d_in[8];
    const float* Wn1   = (const float*)d_in[9];
    const float* bn1   = (const float*)d_in[10];
    const float* Wn2   = (const float*)d_in[11];
    const float* bn2   = (const float*)d_in[12];
    const float* Wc    = (const float*)d_in[13];
    const float* bc    = (const float*)d_in[14];

    char* ws = (char*)d_ws;
    __bf16* xb     = (__bf16*)(ws);                 // 12,800,000
    __bf16* We1S   = (__bf16*)(ws + 12800000);      //     65,536
    __bf16* We2S   = (__bf16*)(ws + 12865536);      //     32,768
    __bf16* Wn1T   = (__bf16*)(ws + 12898304);      //     65,536
    __bf16* Wn2T   = (__bf16*)(ws + 12963840);      //     32,768
    float*  msum   = (float*)(ws + 12996608);       // 25,600,000
    float*  csum   = (float*)(ws + 38596608);       //    600,000
    int*    hist   = (int*)(ws + 39196608);         //    200,000
    int*    off    = (int*)(ws + 39396608);         //    200,064
    int*    cursor = (int*)(ws + 39596672);         //    200,064
    float4* e_geo  = (float4*)(ws + 39796736);      // 12,800,000 (16B aligned)
    int2*   e_nodes= (int2*)(ws + 52596736);        //  6,400,000
    float2* e_gate = (float2*)(ws + 58996736);      //  6,400,000
    int*    bsum   = (int*)(ws + 65396736);         //      1,024 (end 65,397,760)

    float* xout = (float*)d_out;
    float* pout = xout + (size_t)NN * 128;

    // zero msum + csum + hist (contiguous, 26.4 MB)
    hipMemsetAsync(ws + 12996608, 0, 26400000, stream);
    prep_kernel<<<1024, 256, 0, stream>>>(x, We1, We2, Wn1, Wn2, eidx,
                                          xb, We1S, We2S, Wn1T, Wn2T, hist);
    scan_a<<<SCAN_BLOCKS, 256, 0, stream>>>(hist, bsum);
    scan_b<<<1, 256, 0, stream>>>(bsum);
    scan_c<<<SCAN_BLOCKS, 256, 0, stream>>>(hist, bsum, off, cursor);
    scatter_kernel<<<(EE + 255) / 256, 256, 0, stream>>>(eidx, pos, eattr, s, cursor,
                                                         e_geo, e_nodes, e_gate);
    edge_kernel<<<EE / 128, 256, 0, stream>>>(xb, e_geo, e_nodes, e_gate,
                                              We1S, We1, be1, We2S, be2, Wc, bc,
                                              msum, csum);
    node_kernel<<<(NN + 63) / 64, 256, 0, stream>>>(xb, msum, off, Wn1T, bn1, Wn2T, bn2,
                                                    pos, csum, xout, pout);
}